// Round 5
// baseline (432.094 us; speedup 1.0000x reference)
//
#include <hip/hip_runtime.h>

typedef __attribute__((ext_vector_type(4))) float f32x4;
typedef __attribute__((ext_vector_type(8))) short short8;

#define B_ 4
#define N_ 8192
#define E_ 131072
#define R_ 16
#define H_ 128
#define OUT_ 32
#define NKEYS (B_*N_*R_)   /* 524288 */
#define NEDGE (B_*E_)      /* 524288 */

__device__ __forceinline__ unsigned short f2bf(float f){
  unsigned int u = __float_as_uint(f);
  u = (u + 0x7fffu + ((u>>16)&1u)) >> 16;
  return (unsigned short)u;
}
__device__ __forceinline__ float bfh(unsigned u, int hi){
  return __uint_as_float(hi ? (u & 0xffff0000u) : (u << 16));
}
union U8 { unsigned u[4]; short8 s; };
__device__ __forceinline__ short8 u4_to_s8(unsigned a,unsigned b,unsigned c,unsigned d){
  U8 x; x.u[0]=a; x.u[1]=b; x.u[2]=c; x.u[3]=d; return x.s;
}

// ---------------- CSR build: key = ((b*16 + r)*8192 + dst) ----------------

__global__ void hist_k(const int* __restrict__ et, const int* __restrict__ ec,
                       int* __restrict__ cnt){
  int e = blockIdx.x*256 + threadIdx.x;
  int b = e >> 17;                  // E = 2^17
  int dst = et[2*e+1];
  int r  = ec[e];
  atomicAdd(&cnt[(((b<<4)+r)<<13) + dst], 1);
}

__global__ void scan1_k(const int* __restrict__ in, int* __restrict__ out,
                        int* __restrict__ bsum){
  __shared__ int lds[256];
  int t = threadIdx.x;
  int base = blockIdx.x*1024 + t*4;
  int4 v = *(const int4*)(in + base);
  lds[t] = v.x+v.y+v.z+v.w;
  __syncthreads();
  for (int off=1; off<256; off<<=1){
    int x = (t>=off) ? lds[t-off] : 0;
    __syncthreads();
    lds[t] += x;
    __syncthreads();
  }
  if (t==255) bsum[blockIdx.x] = lds[255];
  int pre = (t==0) ? 0 : lds[t-1];
  int4 o;
  o.x = pre; o.y = o.x+v.x; o.z = o.y+v.y; o.w = o.z+v.z;
  *(int4*)(out + base) = o;
}

__global__ void scan2_k(int* __restrict__ bsum){
  __shared__ int lds[256];
  int t = threadIdx.x;
  int2 v = *(const int2*)(bsum + t*2);
  lds[t] = v.x+v.y;
  __syncthreads();
  for (int off=1; off<256; off<<=1){
    int x = (t>=off) ? lds[t-off] : 0;
    __syncthreads();
    lds[t] += x;
    __syncthreads();
  }
  int pre = (t==0) ? 0 : lds[t-1];
  int2 o; o.x = pre; o.y = pre + v.x;
  *(int2*)(bsum + t*2) = o;
}

__global__ void scan3_k(int* __restrict__ out, const int* __restrict__ bsum){
  int t = threadIdx.x;
  int base = blockIdx.x*1024 + t*4;
  int add = bsum[blockIdx.x];
  int4 v = *(int4*)(out + base);
  v.x+=add; v.y+=add; v.z+=add; v.w+=add;
  *(int4*)(out + base) = v;
  if (blockIdx.x==0 && t==0) out[NKEYS] = NEDGE;
}

__global__ void fill_k(const int* __restrict__ et, const int* __restrict__ ec,
                       const float* __restrict__ me, const int* __restrict__ off,
                       int* __restrict__ cur, uint2* __restrict__ erec){
  int e = blockIdx.x*256 + threadIdx.x;
  int b = e >> 17;
  int src = et[2*e];
  int dst = et[2*e+1];
  int r  = ec[e];
  int key = (((b<<4)+r)<<13) + dst;
  int pos = off[key] + atomicAdd(&cur[key], 1);
  erec[pos] = make_uint2((unsigned)src, __float_as_uint(me[e]));
}

// ---------------- feature prep (embed + 3x W-transpose, fused) ----------------

__global__ void prep_k(const int* __restrict__ cls, const float* __restrict__ emb,
                       const float* __restrict__ W1, const float* __restrict__ W2,
                       const float* __restrict__ W3,
                       unsigned short* __restrict__ h,
                       unsigned short* __restrict__ W1t,
                       unsigned short* __restrict__ W2t,
                       unsigned short* __restrict__ W3t){
  int t = blockIdx.x*256 + threadIdx.x;
  if (t < B_*N_*32) {
    int node = t>>5, c = t&31;
    int cl = cls[node];
    float4 v = *(const float4*)(emb + cl*H_ + c*4);
    uint2 o;
    o.x = f2bf(v.x) | ((unsigned int)f2bf(v.y)<<16);
    o.y = f2bf(v.z) | ((unsigned int)f2bf(v.w)<<16);
    *(uint2*)(h + node*H_ + c*4) = o;
  } else {
    int u = t - B_*N_*32;
    if (u < R_*H_*H_) {
      int k = u & 127, n = (u>>7) & 127, r = u >> 14;
      W1t[u] = f2bf(W1[(r*H_ + k)*H_ + n]);
    } else if (u < 2*R_*H_*H_) {
      int u2 = u - R_*H_*H_;
      int k = u2 & 127, n = (u2>>7) & 127, r = u2 >> 14;
      W2t[u2] = f2bf(W2[(r*H_ + k)*H_ + n]);
    } else {
      int u2 = u - 2*R_*H_*H_;
      if (u2 < R_*OUT_*H_) {
        int k = u2 & 127, n = (u2>>7) & 31, r = u2 >> 12;
        W3t[u2] = f2bf(W3[(r*H_ + k)*OUT_ + n]);
      }
    }
  }
}

// ---------------- fused aggregate + GEMM layer (barrier-free waves) --------
// Block = 32 dst rows, 256 threads = 4 waves = 2 relgrps x 2 n-slices.
// Each wave, per rel (8 of them): edge-sum h[src] rows in fp32 DIRECTLY in
// the MFMA A-fragment lane layout (lane (c16,g) owns row mi*16+c16, feats
// ks*32+g*8; the 4 g-lanes x 4 ks jointly read the full 256B h row ->
// coalesced), cvt_pk to bf16 A-frags, MFMA vs register-loaded B-frags.
// No __syncthreads() until the 2-pass epilogue combine (padded LDS, no
// swizzle needed). Speculative 2-rec prefetch per row; rare serial tail.

template<int NOUT>
__global__ __launch_bounds__(256, 3) void layer_k(
    const unsigned short* __restrict__ h_in,   // bf16 [B*N*H]
    const unsigned short* __restrict__ Wt,     // bf16 [R][NOUT][H]
    const int* __restrict__ csr_off,
    const uint2* __restrict__ erec,            // {src, mask bits}
    unsigned short* __restrict__ h_out,        // bf16 relu'd (NOUT=128)
    float* __restrict__ logits)                // fp32 (NOUT=32)
{
  constexpr int NI   = NOUT >> 5;              // 4 (NOUT=128) or 1 (NOUT=32)
  constexpr int CSTR = NOUT + 4;               // padded LDS stride
  __shared__ int rowoff_s[R_*33];              // 2.1 KB
  __shared__ float comb[32*CSTR];              // 16.9 KB / 4.6 KB

  const int tid  = threadIdx.x;
  const int lane = tid & 63;
  const int w    = tid >> 6;                   // 0..3
  const int c16  = lane & 15;
  const int g    = lane >> 4;
  const int relgrp = w >> 1;                   // 0/1 -> rels 0-7 / 8-15
  const int nq   = w & 1;                      // n-slice
  const int nbase = nq * (NI << 4);

  // XCD-batch affinity (grid 1024, bijective): xcd = orig&7 -> b = xcd>>1
  const int orig = blockIdx.x;
  const int xcd  = orig & 7;
  const int b    = xcd >> 1;
  const int dst0 = ((((xcd & 1) << 7) + (orig >> 3))) << 5;   // tile*32
  const char* hbB = (const char*)h_in + ((size_t)b << 21);    // b*N*H*2B

  for (int i = tid; i < R_*33; i += 256) {
    int r = i / 33, rr = i - r*33;
    rowoff_s[i] = csr_off[(((b<<4) + r) << 13) + dst0 + rr];
  }
  __syncthreads();

  f32x4 acc[2][NI];
  #pragma unroll
  for (int mi=0; mi<2; ++mi)
    #pragma unroll
    for (int ni=0; ni<NI; ++ni)
      acc[mi][ni] = f32x4{0.f,0.f,0.f,0.f};

#define UNP8(FAK, V, M) do { \
  FAK[0] += M * bfh(V.x,0); FAK[1] += M * bfh(V.x,1); \
  FAK[2] += M * bfh(V.y,0); FAK[3] += M * bfh(V.y,1); \
  FAK[4] += M * bfh(V.z,0); FAK[5] += M * bfh(V.z,1); \
  FAK[6] += M * bfh(V.w,0); FAK[7] += M * bfh(V.w,1); \
} while(0)

#define EDGE_FMA(FA, RC) do { \
  float m_ = __uint_as_float((RC).y); \
  const char* hp_ = hbB + ((size_t)(RC).x << 8) + (g<<4); \
  uint4 v0_ = *(const uint4*)(hp_); \
  uint4 v1_ = *(const uint4*)(hp_ + 64); \
  uint4 v2_ = *(const uint4*)(hp_ + 128); \
  uint4 v3_ = *(const uint4*)(hp_ + 192); \
  UNP8(FA[0], v0_, m_); UNP8(FA[1], v1_, m_); \
  UNP8(FA[2], v2_, m_); UNP8(FA[3], v3_, m_); \
} while(0)

#define GATHER_MI(AF, rsv, rev, RC0, RC1) do { \
  float fa_[4][8]; \
  _Pragma("unroll") \
  for (int k_=0;k_<4;++k_) \
    _Pragma("unroll") \
    for (int j_=0;j_<8;++j_) fa_[k_][j_] = 0.f; \
  int cn_ = (rev) - (rsv); \
  if (cn_ > 0) { EDGE_FMA(fa_, RC0); } \
  if (cn_ > 1) { EDGE_FMA(fa_, RC1); } \
  for (int e_=2; e_<cn_; ++e_) { uint2 rc_ = erec[(rsv)+e_]; EDGE_FMA(fa_, rc_); } \
  _Pragma("unroll") \
  for (int k_=0;k_<4;++k_) { \
    unsigned u0_,u1_,u2_,u3_; \
    asm("v_cvt_pk_bf16_f32 %0, %1, %2" : "=v"(u0_) : "v"(fa_[k_][0]), "v"(fa_[k_][1])); \
    asm("v_cvt_pk_bf16_f32 %0, %1, %2" : "=v"(u1_) : "v"(fa_[k_][2]), "v"(fa_[k_][3])); \
    asm("v_cvt_pk_bf16_f32 %0, %1, %2" : "=v"(u2_) : "v"(fa_[k_][4]), "v"(fa_[k_][5])); \
    asm("v_cvt_pk_bf16_f32 %0, %1, %2" : "=v"(u3_) : "v"(fa_[k_][6]), "v"(fa_[k_][7])); \
    AF[k_] = u4_to_s8(u0_,u1_,u2_,u3_); \
  } \
} while(0)

  for (int j = 0; j < 8; ++j) {
    const int r = relgrp*8 + j;
    const int ro = r*33 + c16;
    int rs0 = rowoff_s[ro],    re0 = rowoff_s[ro+1];
    int rs1 = rowoff_s[ro+16], re1 = rowoff_s[ro+17];
    uint2 rc00, rc01, rc10, rc11;
    if (re0 > rs0)   rc00 = erec[rs0];
    if (re0 > rs0+1) rc01 = erec[rs0+1];
    if (re1 > rs1)   rc10 = erec[rs1];
    if (re1 > rs1+1) rc11 = erec[rs1+1];

    short8 af0[4], af1[4];
    GATHER_MI(af0, rs0, re0, rc00, rc01);
    GATHER_MI(af1, rs1, re1, rc10, rc11);

    const unsigned short* Wr = Wt + (((size_t)r * NOUT) << 7);
    #pragma unroll
    for (int ks = 0; ks < 4; ++ks) {
      #pragma unroll
      for (int ni = 0; ni < NI; ++ni) {
        short8 bq = *(const short8*)(Wr + ((nbase + ni*16 + c16) << 7) + (ks<<5) + (g<<3));
        acc[0][ni] = __builtin_amdgcn_mfma_f32_16x16x32_bf16(af0[ks], bq, acc[0][ni], 0,0,0);
        acc[1][ni] = __builtin_amdgcn_mfma_f32_16x16x32_bf16(af1[ks], bq, acc[1][ni], 0,0,0);
      }
    }
  }

  // ---- epilogue: combine the 2 relgrp partials (padded LDS, 2 barriers) ----
  if (w < 2) {
    #pragma unroll
    for (int mi=0; mi<2; ++mi)
      #pragma unroll
      for (int ni=0; ni<NI; ++ni)
        #pragma unroll
        for (int jj=0; jj<4; ++jj)
          comb[(mi*16 + (g<<2) + jj)*CSTR + nbase + ni*16 + c16] = acc[mi][ni][jj];
  }
  __syncthreads();
  if (w >= 2) {
    #pragma unroll
    for (int mi=0; mi<2; ++mi)
      #pragma unroll
      for (int ni=0; ni<NI; ++ni)
        #pragma unroll
        for (int jj=0; jj<4; ++jj)
          comb[(mi*16 + (g<<2) + jj)*CSTR + nbase + ni*16 + c16] += acc[mi][ni][jj];
  }
  __syncthreads();

  const int rrow = tid >> 3;                 // 0..31
  const size_t node = (size_t)((b<<13) + dst0 + rrow);
  if constexpr (NOUT == 128) {
    const int c0 = (tid & 7) << 4;           // 16 floats
    const float* cp = &comb[rrow*CSTR + c0];
    unsigned o[8];
    #pragma unroll
    for (int t2 = 0; t2 < 8; ++t2) {
      float lo = fmaxf(cp[2*t2],   0.f);
      float hi = fmaxf(cp[2*t2+1], 0.f);
      asm("v_cvt_pk_bf16_f32 %0, %1, %2" : "=v"(o[t2]) : "v"(lo), "v"(hi));
    }
    uint4* dp = (uint4*)((char*)h_out + (node << 8) + (c0 << 1));
    dp[0] = make_uint4(o[0],o[1],o[2],o[3]);
    dp[1] = make_uint4(o[4],o[5],o[6],o[7]);
  } else {
    const int c0 = (tid & 7) << 2;           // 4 floats
    float4 vv = *(const float4*)&comb[rrow*CSTR + c0];
    *(float4*)(logits + (node << 5) + c0) = vv;
  }
#undef GATHER_MI
#undef EDGE_FMA
#undef UNP8
}

__global__ void softmax_k(const float* __restrict__ logits,
                          const float* __restrict__ mobj,
                          float* __restrict__ out){
  int row = blockIdx.x*256 + threadIdx.x;  // 32768 rows
  float v[32];
  const float4* p = (const float4*)(logits + row*32);
  #pragma unroll
  for (int i=0;i<8;i++){
    float4 x = p[i];
    v[4*i]=x.x; v[4*i+1]=x.y; v[4*i+2]=x.z; v[4*i+3]=x.w;
  }
  float mx = v[0];
  #pragma unroll
  for (int i=1;i<32;i++) mx = fmaxf(mx, v[i]);
  float s = 0.f;
  #pragma unroll
  for (int i=0;i<32;i++){ v[i] = __expf(v[i]-mx); s += v[i]; }
  float sc = mobj[row] / s;
  float4* qo = (float4*)(out + row*32);
  #pragma unroll
  for (int i=0;i<8;i++){
    float4 x;
    x.x=v[4*i]*sc; x.y=v[4*i+1]*sc; x.z=v[4*i+2]*sc; x.w=v[4*i+3]*sc;
    qo[i] = x;
  }
}

extern "C" void kernel_launch(void* const* d_in, const int* in_sizes, int n_in,
                              void* d_out, int out_size, void* d_ws, size_t ws_size,
                              hipStream_t stream){
  const int*   cls   = (const int*)  d_in[0];
  // d_in[1] states_objects: unused by reference
  const int*   et    = (const int*)  d_in[2];
  const int*   ec    = (const int*)  d_in[3];
  const float* mobj  = (const float*)d_in[4];
  const float* medge = (const float*)d_in[5];
  const float* emb   = (const float*)d_in[6];
  const float* W1    = (const float*)d_in[7];
  const float* W2    = (const float*)d_in[8];
  const float* W3    = (const float*)d_in[9];
  float* out = (float*)d_out;

  char* ws = (char*)d_ws;
  size_t o = 0;
  auto alloc = [&](size_t bytes)->char*{
    char* p = ws + o;
    o += (bytes + 255) & ~(size_t)255;
    return p;
  };
  unsigned short* hA    = (unsigned short*)alloc((size_t)B_*N_*H_*2);
  unsigned short* hB    = (unsigned short*)alloc((size_t)B_*N_*H_*2);
  float*          lg    = (float*)alloc((size_t)B_*N_*OUT_*4);
  unsigned short* W1t   = (unsigned short*)alloc((size_t)R_*H_*H_*2);
  unsigned short* W2t   = (unsigned short*)alloc((size_t)R_*H_*H_*2);
  unsigned short* W3t   = (unsigned short*)alloc((size_t)R_*OUT_*H_*2);
  int*            cnt   = (int*)alloc((size_t)NKEYS*4);
  int*            off   = (int*)alloc((size_t)(NKEYS+1)*4);
  int*            bsum  = (int*)alloc(512*4);
  uint2*          erec  = (uint2*)alloc((size_t)NEDGE*8);
  (void)ws_size; (void)in_sizes; (void)n_in; (void)out_size;

  // CSR build: histogram -> exclusive scan -> fill (key = (b, rel, dst))
  hipMemsetAsync(cnt, 0, (size_t)NKEYS*4, stream);
  hipLaunchKernelGGL(hist_k,  dim3(NEDGE/256), dim3(256), 0, stream, et, ec, cnt);
  hipLaunchKernelGGL(scan1_k, dim3(512), dim3(256), 0, stream, cnt, off, bsum);
  hipLaunchKernelGGL(scan2_k, dim3(1),   dim3(256), 0, stream, bsum);
  hipLaunchKernelGGL(scan3_k, dim3(512), dim3(256), 0, stream, off, bsum);
  hipMemsetAsync(cnt, 0, (size_t)NKEYS*4, stream);   // cnt -> cursor
  hipLaunchKernelGGL(fill_k,  dim3(NEDGE/256), dim3(256), 0, stream, et, ec, medge, off, cnt, erec);

  // h0 = bf16(embed[class]);  W -> bf16 [r][n][k]  (fused)
  hipLaunchKernelGGL(prep_k, dim3((B_*N_*32 + 2*R_*H_*H_ + R_*OUT_*H_)/256), dim3(256), 0, stream,
                     cls, emb, W1, W2, W3, hA, W1t, W2t, W3t);

  // 3 fused aggregate+GEMM layers, then softmax*mask
  hipLaunchKernelGGL((layer_k<128>), dim3(B_*N_/32), dim3(256), 0, stream,
                     hA, W1t, off, erec, hB, (float*)nullptr);
  hipLaunchKernelGGL((layer_k<128>), dim3(B_*N_/32), dim3(256), 0, stream,
                     hB, W2t, off, erec, hA, (float*)nullptr);
  hipLaunchKernelGGL((layer_k<32>),  dim3(B_*N_/32), dim3(256), 0, stream,
                     hA, W3t, off, erec, (unsigned short*)nullptr, lg);
  hipLaunchKernelGGL(softmax_k, dim3(B_*N_/256), dim3(256), 0, stream, lg, mobj, out);
}